// Round 4
// baseline (856.193 us; speedup 1.0000x reference)
//
#include <hip/hip_runtime.h>

#define N_NODES 100000
#define N_EDGES 1600000
#define D_IN 128
#define D_OUT 64
#define NB 391          // ceil(100000/256) buckets of 256 nodes
#define NCPAD 100352    // NB*256 rounded up, zero-padded counts
#define EPB 4096        // edges per partition block
#define NPART 391       // ceil(1600000/4096)

// ws layout (4B units):
//   counts int[NCPAD] | dinv f[N] | hs f[N*64] | part int[E] |
//   bsum int[392] | eoff int[392] | ecur int[391]

__global__ __launch_bounds__(256) void k_hist(const int* __restrict__ dst,
                                              int* __restrict__ counts) {
    int e = blockIdx.x * 256 + threadIdx.x;
    if (e < N_EDGES) atomicAdd(&counts[dst[e]], 1);
}

__global__ __launch_bounds__(256) void k_dinv(const int* __restrict__ counts,
                                              float* __restrict__ dinv) {
    int i = blockIdx.x * 256 + threadIdx.x;
    if (i < N_NODES) dinv[i] = rsqrtf((float)counts[i] + 1.0f);
}

// One wave per bucket: sum 256 counts.
__global__ __launch_bounds__(64) void k_bsum(const int* __restrict__ counts,
                                             int* __restrict__ bsum) {
    int b = blockIdx.x, lane = threadIdx.x;
    int4 c = ((const int4*)(counts + b * 256))[lane];
    int s = c.x + c.y + c.z + c.w;
#pragma unroll
    for (int d = 32; d >= 1; d >>= 1) s += __shfl_down(s, d);
    if (lane == 0) bsum[b] = s;
}

// Single block: exclusive scan of 391 bucket sums.
__global__ __launch_bounds__(512) void k_bscan(const int* __restrict__ bsum,
                                               int* __restrict__ eoff,
                                               int* __restrict__ ecur) {
    __shared__ int s[512];
    int t = threadIdx.x;
    int v = (t < NB) ? bsum[t] : 0;
    s[t] = v;
    __syncthreads();
    for (int d = 1; d < 512; d <<= 1) {
        int u = (t >= d) ? s[t - d] : 0;
        __syncthreads();
        s[t] += u;
        __syncthreads();
    }
    if (t < NB) {
        int excl = s[t] - v;
        eoff[t] = excl;
        ecur[t] = excl;
        if (t == NB - 1) eoff[NB] = s[t];
    }
}

// LDS-staged bucket partition: packed = (src<<8)|(dst&255), grouped by dst>>8.
__global__ __launch_bounds__(256) void k_part(const int* __restrict__ src,
                                              const int* __restrict__ dst,
                                              int* __restrict__ ecur,
                                              int* __restrict__ part) {
    __shared__ int lh[NB];
    __shared__ int lbase[NB + 1];
    __shared__ int ldelta[NB];
    __shared__ int lcur[NB];
    __shared__ int stage[EPB];
    __shared__ unsigned short sbk[EPB];
    const int t = threadIdx.x;
    const int e0 = blockIdx.x * EPB;
    for (int i = t; i < NB; i += 256) lh[i] = 0;
    __syncthreads();
    int p[16];
    short bk[16];
#pragma unroll
    for (int i = 0; i < 16; i++) {
        int e = e0 + i * 256 + t;
        bk[i] = -1;
        p[i] = 0;
        if (e < N_EDGES) {
            int s = src[e], d = dst[e];
            int b = d >> 8;
            bk[i] = (short)b;
            p[i] = (s << 8) | (d & 255);
            atomicAdd(&lh[b], 1);
        }
    }
    __syncthreads();
    // exclusive scan of lh[0..NB) by wave 0 (7 counters per lane)
    if (t < 64) {
        int c[7];
        int tot = 0;
#pragma unroll
        for (int j = 0; j < 7; j++) {
            int idx = t * 7 + j;
            c[j] = (idx < NB) ? lh[idx] : 0;
            tot += c[j];
        }
        int v = tot;
#pragma unroll
        for (int d = 1; d < 64; d <<= 1) {
            int u = __shfl_up(v, d);
            if (t >= d) v += u;
        }
        int run = v - tot;
#pragma unroll
        for (int j = 0; j < 7; j++) {
            int idx = t * 7 + j;
            if (idx < NB) lbase[idx] = run;
            run += c[j];
        }
        if (t == 63) lbase[NB] = run;  // total valid edges this block
    }
    __syncthreads();
    for (int i = t; i < NB; i += 256) {
        int cnt = lh[i];
        lcur[i] = lbase[i];
        if (cnt > 0) {
            int g = atomicAdd(&ecur[i], cnt);
            ldelta[i] = g - lbase[i];
        }
    }
    __syncthreads();
#pragma unroll
    for (int i = 0; i < 16; i++) {
        if (bk[i] >= 0) {
            int slot = atomicAdd(&lcur[bk[i]], 1);
            stage[slot] = p[i];
            sbk[slot] = (unsigned short)bk[i];
        }
    }
    __syncthreads();
    int nval = lbase[NB];
    for (int s = t; s < nval; s += 256) {
        part[ldelta[sbk[s]] + s] = stage[s];
    }
}

// GEMM: 16 rows/block (4 rows per wave), lane = output column.
// hs = (x@w) * dinv[row].
__global__ __launch_bounds__(256) void k_gemm(const float* __restrict__ x,
                                              const float* __restrict__ w,
                                              const float* __restrict__ dinv,
                                              float* __restrict__ hs) {
    __shared__ float wl[D_IN * D_OUT];  // 32 KB
    __shared__ float xl[16][D_IN];      // 8 KB
    const int t = threadIdx.x;
    for (int i = t; i < D_IN * D_OUT; i += 256) wl[i] = w[i];
    const int row0 = blockIdx.x * 16;
    const float4* xg = (const float4*)(x + (size_t)row0 * D_IN);
    float4* xs = (float4*)&xl[0][0];
    xs[t]       = xg[t];
    xs[t + 256] = xg[t + 256];
    __syncthreads();

    const int wave = t >> 6, lane = t & 63;
    const int r0 = wave * 4;
    float acc0 = 0.f, acc1 = 0.f, acc2 = 0.f, acc3 = 0.f;
#pragma unroll
    for (int k0 = 0; k0 < D_IN; k0 += 4) {
        float4 x0 = *(const float4*)&xl[r0 + 0][k0];
        float4 x1 = *(const float4*)&xl[r0 + 1][k0];
        float4 x2 = *(const float4*)&xl[r0 + 2][k0];
        float4 x3 = *(const float4*)&xl[r0 + 3][k0];
        float w0 = wl[(k0 + 0) * 64 + lane];
        float w1 = wl[(k0 + 1) * 64 + lane];
        float w2 = wl[(k0 + 2) * 64 + lane];
        float w3 = wl[(k0 + 3) * 64 + lane];
        acc0 = fmaf(x0.w, w3, fmaf(x0.z, w2, fmaf(x0.y, w1, fmaf(x0.x, w0, acc0))));
        acc1 = fmaf(x1.w, w3, fmaf(x1.z, w2, fmaf(x1.y, w1, fmaf(x1.x, w0, acc1))));
        acc2 = fmaf(x2.w, w3, fmaf(x2.z, w2, fmaf(x2.y, w1, fmaf(x2.x, w0, acc2))));
        acc3 = fmaf(x3.w, w3, fmaf(x3.z, w2, fmaf(x3.y, w1, fmaf(x3.x, w0, acc3))));
    }
    const int gr = row0 + r0;
    hs[(size_t)(gr + 0) * 64 + lane] = acc0 * dinv[gr + 0];
    hs[(size_t)(gr + 1) * 64 + lane] = acc1 * dinv[gr + 1];
    hs[(size_t)(gr + 2) * 64 + lane] = acc2 * dinv[gr + 2];
    hs[(size_t)(gr + 3) * 64 + lane] = acc3 * dinv[gr + 3];
}

// One block per bucket: LDS accumulators acc[256][64], ds_add per edge,
// fused epilogue (self-loop, dinv, bias, relu).
__global__ __launch_bounds__(512, 2) void k_agg(const int* __restrict__ eoff,
                                                const int* __restrict__ part,
                                                const float* __restrict__ dinv,
                                                const float* __restrict__ hs,
                                                const float* __restrict__ bias,
                                                float* __restrict__ out) {
    __shared__ float acc[256 * 64];  // 64 KB
    const int t = threadIdx.x, b = blockIdx.x;
    float4* a4 = (float4*)acc;
#pragma unroll
    for (int i = 0; i < 8; i++) a4[t + i * 512] = make_float4(0.f, 0.f, 0.f, 0.f);
    __syncthreads();
    const int lane = t & 63, w = t >> 6;
    const int beg = eoff[b], end = eoff[b + 1];
    for (int base = beg + w * 64; base < end; base += 512) {
        int m = end - base;
        int pk = (lane < m) ? part[base + lane] : 0;
        if (m >= 64) {
#pragma unroll 8
            for (int k = 0; k < 64; k++) {
                int pp = __shfl(pk, k);
                atomicAdd(&acc[(pp & 255) * 64 + lane], hs[(size_t)(pp >> 8) * 64 + lane]);
            }
        } else {
            for (int k = 0; k < m; k++) {
                int pp = __shfl(pk, k);
                atomicAdd(&acc[(pp & 255) * 64 + lane], hs[(size_t)(pp >> 8) * 64 + lane]);
            }
        }
    }
    __syncthreads();
    float bb = bias[lane];
#pragma unroll
    for (int it = 0; it < 32; it++) {
        int r = w + it * 8;
        int n = b * 256 + r;
        if (n < N_NODES) {
            float dv = dinv[n];
            // hs already carries dinv[row]: self term = hs[n]*dv, neighbors = dv*acc.
            float v = dv * (acc[r * 64 + lane] + hs[(size_t)n * 64 + lane]) + bb;
            out[(size_t)n * 64 + lane] = v > 0.f ? v : 0.f;
        }
    }
}

extern "C" void kernel_launch(void* const* d_in, const int* in_sizes, int n_in,
                              void* d_out, int out_size, void* d_ws, size_t ws_size,
                              hipStream_t stream) {
    const float* x    = (const float*)d_in[0];
    const int*   ei   = (const int*)d_in[1];   // [2][E] row-major
    const float* w    = (const float*)d_in[2];
    const float* bias = (const float*)d_in[3];
    float* out = (float*)d_out;

    int*   counts = (int*)d_ws;                       // NCPAD
    float* dinv   = (float*)(counts + NCPAD);         // N
    float* hs     = dinv + N_NODES;                   // N*64
    int*   part   = (int*)(hs + (size_t)N_NODES * 64);// E
    int*   bsum   = part + N_EDGES;                   // 392
    int*   eoff   = bsum + 392;                       // NB+1
    int*   ecur   = eoff + 392;                       // NB

    const int* srcI = ei;
    const int* dstI = ei + N_EDGES;

    hipMemsetAsync(counts, 0, NCPAD * sizeof(int), stream);
    hipLaunchKernelGGL(k_hist, dim3((N_EDGES + 255) / 256), dim3(256), 0, stream, dstI, counts);
    hipLaunchKernelGGL(k_dinv, dim3((N_NODES + 255) / 256), dim3(256), 0, stream, counts, dinv);
    hipLaunchKernelGGL(k_bsum, dim3(NB), dim3(64), 0, stream, counts, bsum);
    hipLaunchKernelGGL(k_bscan, dim3(1), dim3(512), 0, stream, bsum, eoff, ecur);
    hipLaunchKernelGGL(k_part, dim3(NPART), dim3(256), 0, stream, srcI, dstI, ecur, part);
    hipLaunchKernelGGL(k_gemm, dim3(N_NODES / 16), dim3(256), 0, stream, x, w, dinv, hs);
    hipLaunchKernelGGL(k_agg, dim3(NB), dim3(512), 0, stream, eoff, part, dinv, hs, bias, out);
}

// Round 5
// 218.585 us; speedup vs baseline: 3.9170x; 3.9170x over previous
//
#include <hip/hip_runtime.h>

#define N_NODES 100000
#define N_EDGES 1600000
#define D_IN 128
#define D_OUT 64
#define NB 391          // ceil(100000/256) buckets of 256 dst nodes
#define NCPAD 100352    // NB*256, zero-padded counts
#define EPB 4096        // edges per partition block
#define NPART 391       // ceil(1600000/4096)
#define BKT_CAP 4864    // max edges per bucket (mean 4096, sigma 64 -> 12 sigma)

// ws layout (4B units):
//   counts int[NCPAD] | dinv f[N] | hs f[N*64] | part int[E] |
//   bsum int[392] | eoff int[392] | ecur int[391] | noff int[N]

__global__ __launch_bounds__(256) void k_hist(const int* __restrict__ dst,
                                              int* __restrict__ counts) {
    int e = blockIdx.x * 256 + threadIdx.x;
    if (e < N_EDGES) atomicAdd(&counts[dst[e]], 1);
}

__global__ __launch_bounds__(256) void k_dinv(const int* __restrict__ counts,
                                              float* __restrict__ dinv) {
    int i = blockIdx.x * 256 + threadIdx.x;
    if (i < N_NODES) dinv[i] = rsqrtf((float)counts[i] + 1.0f);
}

// One wave per bucket: sum 256 counts.
__global__ __launch_bounds__(64) void k_bsum(const int* __restrict__ counts,
                                             int* __restrict__ bsum) {
    int b = blockIdx.x, lane = threadIdx.x;
    int4 c = ((const int4*)(counts + b * 256))[lane];
    int s = c.x + c.y + c.z + c.w;
#pragma unroll
    for (int d = 32; d >= 1; d >>= 1) s += __shfl_down(s, d);
    if (lane == 0) bsum[b] = s;
}

// Single block: exclusive scan of 391 bucket sums.
__global__ __launch_bounds__(512) void k_bscan(const int* __restrict__ bsum,
                                               int* __restrict__ eoff,
                                               int* __restrict__ ecur) {
    __shared__ int s[512];
    int t = threadIdx.x;
    int v = (t < NB) ? bsum[t] : 0;
    s[t] = v;
    __syncthreads();
    for (int d = 1; d < 512; d <<= 1) {
        int u = (t >= d) ? s[t - d] : 0;
        __syncthreads();
        s[t] += u;
        __syncthreads();
    }
    if (t < NB) {
        int excl = s[t] - v;
        eoff[t] = excl;
        ecur[t] = excl;
        if (t == NB - 1) eoff[NB] = s[t];
    }
}

// LDS-staged bucket partition: packed = (src<<8)|(dst&255), grouped by dst>>8.
__global__ __launch_bounds__(256) void k_part(const int* __restrict__ src,
                                              const int* __restrict__ dst,
                                              int* __restrict__ ecur,
                                              int* __restrict__ part) {
    __shared__ int lh[NB];
    __shared__ int lbase[NB + 1];
    __shared__ int ldelta[NB];
    __shared__ int lcur[NB];
    __shared__ int stage[EPB];
    __shared__ unsigned short sbk[EPB];
    const int t = threadIdx.x;
    const int e0 = blockIdx.x * EPB;
    for (int i = t; i < NB; i += 256) lh[i] = 0;
    __syncthreads();
    int p[16];
    short bk[16];
#pragma unroll
    for (int i = 0; i < 16; i++) {
        int e = e0 + i * 256 + t;
        bk[i] = -1;
        p[i] = 0;
        if (e < N_EDGES) {
            int s = src[e], d = dst[e];
            int b = d >> 8;
            bk[i] = (short)b;
            p[i] = (s << 8) | (d & 255);
            atomicAdd(&lh[b], 1);
        }
    }
    __syncthreads();
    // exclusive scan of lh[0..NB) by wave 0 (7 counters per lane)
    if (t < 64) {
        int c[7];
        int tot = 0;
#pragma unroll
        for (int j = 0; j < 7; j++) {
            int idx = t * 7 + j;
            c[j] = (idx < NB) ? lh[idx] : 0;
            tot += c[j];
        }
        int v = tot;
#pragma unroll
        for (int d = 1; d < 64; d <<= 1) {
            int u = __shfl_up(v, d);
            if (t >= d) v += u;
        }
        int run = v - tot;
#pragma unroll
        for (int j = 0; j < 7; j++) {
            int idx = t * 7 + j;
            if (idx < NB) lbase[idx] = run;
            run += c[j];
        }
        if (t == 63) lbase[NB] = run;  // total valid edges this block
    }
    __syncthreads();
    for (int i = t; i < NB; i += 256) {
        int cnt = lh[i];
        lcur[i] = lbase[i];
        if (cnt > 0) {
            int g = atomicAdd(&ecur[i], cnt);
            ldelta[i] = g - lbase[i];
        }
    }
    __syncthreads();
#pragma unroll
    for (int i = 0; i < 16; i++) {
        if (bk[i] >= 0) {
            int slot = atomicAdd(&lcur[bk[i]], 1);
            stage[slot] = p[i];
            sbk[slot] = (unsigned short)bk[i];
        }
    }
    __syncthreads();
    int nval = lbase[NB];
    for (int s = t; s < nval; s += 256) {
        part[ldelta[sbk[s]] + s] = stage[s];
    }
}

// One block per bucket: counting sort by dst low byte. Rewrites part[beg..end)
// in place as sorted src values; emits per-node global offsets noff.
__global__ __launch_bounds__(256) void k_sort(const int* __restrict__ eoff,
                                              int* __restrict__ part,
                                              int* __restrict__ noff) {
    __shared__ int lcnt[256], loff[256], lcur[256];
    __shared__ int wsum[4];
    __shared__ int stage[BKT_CAP];
    const int t = threadIdx.x, b = blockIdx.x;
    const int beg = eoff[b], end = eoff[b + 1];
    const int m = end - beg;
    lcnt[t] = 0;
    __syncthreads();
    for (int i = t; i < m; i += 256) atomicAdd(&lcnt[part[beg + i] & 255], 1);
    __syncthreads();
    // exclusive scan of 256 counters
    int c = lcnt[t];
    int v = c;
    int lane = t & 63, w = t >> 6;
#pragma unroll
    for (int d = 1; d < 64; d <<= 1) {
        int u = __shfl_up(v, d);
        if (lane >= d) v += u;
    }
    if (lane == 63) wsum[w] = v;
    __syncthreads();
    int woff = 0;
#pragma unroll
    for (int k = 0; k < 4; k++) woff += (k < w) ? wsum[k] : 0;
    int excl = woff + v - c;
    loff[t] = excl;
    lcur[t] = excl;
    int node = b * 256 + t;
    if (node < N_NODES) noff[node] = beg + excl;
    __syncthreads();
    for (int i = t; i < m; i += 256) {
        int pk = part[beg + i];
        int slot = atomicAdd(&lcur[pk & 255], 1);
        stage[slot] = pk >> 8;  // unpack src
    }
    __syncthreads();
    for (int i = t; i < m; i += 256) part[beg + i] = stage[i];
}

// GEMM: 16 rows/block (4 rows per wave), lane = output column.
// hs = (x@w) * dinv[row].
__global__ __launch_bounds__(256) void k_gemm(const float* __restrict__ x,
                                              const float* __restrict__ w,
                                              const float* __restrict__ dinv,
                                              float* __restrict__ hs) {
    __shared__ float wl[D_IN * D_OUT];  // 32 KB
    __shared__ float xl[16][D_IN];      // 8 KB
    const int t = threadIdx.x;
    for (int i = t; i < D_IN * D_OUT; i += 256) wl[i] = w[i];
    const int row0 = blockIdx.x * 16;
    const float4* xg = (const float4*)(x + (size_t)row0 * D_IN);
    float4* xs = (float4*)&xl[0][0];
    xs[t]       = xg[t];
    xs[t + 256] = xg[t + 256];
    __syncthreads();

    const int wave = t >> 6, lane = t & 63;
    const int r0 = wave * 4;
    float acc0 = 0.f, acc1 = 0.f, acc2 = 0.f, acc3 = 0.f;
#pragma unroll
    for (int k0 = 0; k0 < D_IN; k0 += 4) {
        float4 x0 = *(const float4*)&xl[r0 + 0][k0];
        float4 x1 = *(const float4*)&xl[r0 + 1][k0];
        float4 x2 = *(const float4*)&xl[r0 + 2][k0];
        float4 x3 = *(const float4*)&xl[r0 + 3][k0];
        float w0 = wl[(k0 + 0) * 64 + lane];
        float w1 = wl[(k0 + 1) * 64 + lane];
        float w2 = wl[(k0 + 2) * 64 + lane];
        float w3 = wl[(k0 + 3) * 64 + lane];
        acc0 = fmaf(x0.w, w3, fmaf(x0.z, w2, fmaf(x0.y, w1, fmaf(x0.x, w0, acc0))));
        acc1 = fmaf(x1.w, w3, fmaf(x1.z, w2, fmaf(x1.y, w1, fmaf(x1.x, w0, acc1))));
        acc2 = fmaf(x2.w, w3, fmaf(x2.z, w2, fmaf(x2.y, w1, fmaf(x2.x, w0, acc2))));
        acc3 = fmaf(x3.w, w3, fmaf(x3.z, w2, fmaf(x3.y, w1, fmaf(x3.x, w0, acc3))));
    }
    const int gr = row0 + r0;
    hs[(size_t)(gr + 0) * 64 + lane] = acc0 * dinv[gr + 0];
    hs[(size_t)(gr + 1) * 64 + lane] = acc1 * dinv[gr + 1];
    hs[(size_t)(gr + 2) * 64 + lane] = acc2 * dinv[gr + 2];
    hs[(size_t)(gr + 3) * 64 + lane] = acc3 * dinv[gr + 3];
}

// One wave per node, lane = output column. Register accumulation with 4
// independent accumulators for MLP; fused self-loop, dinv, bias, relu.
__global__ __launch_bounds__(256) void k_agg(const int* __restrict__ noff,
                                             const int* __restrict__ counts,
                                             const int* __restrict__ ssrc,
                                             const float* __restrict__ dinv,
                                             const float* __restrict__ hs,
                                             const float* __restrict__ bias,
                                             float* __restrict__ out) {
    int t = blockIdx.x * 256 + threadIdx.x;
    int node = t >> 6, lane = t & 63;
    if (node >= N_NODES) return;
    int beg = noff[node];
    int cnt = counts[node];
    float a0 = hs[(size_t)node * 64 + lane];  // self-loop term (carries dinv[node])
    float a1 = 0.f, a2 = 0.f, a3 = 0.f;
    for (int base = 0; base < cnt; base += 64) {
        int m = min(64, cnt - base);
        int sl = (base + lane < cnt) ? ssrc[beg + base + lane] : 0;
        int k = 0;
        for (; k + 4 <= m; k += 4) {
            int s0 = __shfl(sl, k), s1 = __shfl(sl, k + 1);
            int s2 = __shfl(sl, k + 2), s3 = __shfl(sl, k + 3);
            a0 += hs[(size_t)s0 * 64 + lane];
            a1 += hs[(size_t)s1 * 64 + lane];
            a2 += hs[(size_t)s2 * 64 + lane];
            a3 += hs[(size_t)s3 * 64 + lane];
        }
        for (; k < m; k++) {
            int s = __shfl(sl, k);
            a0 += hs[(size_t)s * 64 + lane];
        }
    }
    float dv = dinv[node];
    float vv = dv * (a0 + a1 + a2 + a3) + bias[lane];
    out[(size_t)node * 64 + lane] = vv > 0.f ? vv : 0.f;
}

extern "C" void kernel_launch(void* const* d_in, const int* in_sizes, int n_in,
                              void* d_out, int out_size, void* d_ws, size_t ws_size,
                              hipStream_t stream) {
    const float* x    = (const float*)d_in[0];
    const int*   ei   = (const int*)d_in[1];   // [2][E] row-major
    const float* w    = (const float*)d_in[2];
    const float* bias = (const float*)d_in[3];
    float* out = (float*)d_out;

    int*   counts = (int*)d_ws;                        // NCPAD
    float* dinv   = (float*)(counts + NCPAD);          // N
    float* hs     = dinv + N_NODES;                    // N*64
    int*   part   = (int*)(hs + (size_t)N_NODES * 64); // E
    int*   bsum   = part + N_EDGES;                    // 392
    int*   eoff   = bsum + 392;                        // NB+1
    int*   ecur   = eoff + 392;                        // NB
    int*   noff   = ecur + NB;                         // N

    const int* srcI = ei;
    const int* dstI = ei + N_EDGES;

    hipMemsetAsync(counts, 0, NCPAD * sizeof(int), stream);
    hipLaunchKernelGGL(k_hist, dim3((N_EDGES + 255) / 256), dim3(256), 0, stream, dstI, counts);
    hipLaunchKernelGGL(k_dinv, dim3((N_NODES + 255) / 256), dim3(256), 0, stream, counts, dinv);
    hipLaunchKernelGGL(k_bsum, dim3(NB), dim3(64), 0, stream, counts, bsum);
    hipLaunchKernelGGL(k_bscan, dim3(1), dim3(512), 0, stream, bsum, eoff, ecur);
    hipLaunchKernelGGL(k_part, dim3(NPART), dim3(256), 0, stream, srcI, dstI, ecur, part);
    hipLaunchKernelGGL(k_sort, dim3(NB), dim3(256), 0, stream, eoff, part, noff);
    hipLaunchKernelGGL(k_gemm, dim3(N_NODES / 16), dim3(256), 0, stream, x, w, dinv, hs);
    hipLaunchKernelGGL(k_agg, dim3((N_NODES * 64) / 256), dim3(256), 0, stream,
                       noff, counts, part, dinv, hs, bias, out);
}

// Round 6
// 162.889 us; speedup vs baseline: 5.2563x; 1.3419x over previous
//
#include <hip/hip_runtime.h>

#define N_NODES 100000
#define N_EDGES 1600000
#define D_IN 128
#define D_OUT 64
#define NB 391          // ceil(100000/256) buckets of 256 dst nodes
#define EPB 4096        // edges per block in bhist/part
#define NPART 391       // ceil(1600000/4096)
#define BKT_CAP 4864    // max edges per bucket (mean 4096, sigma ~64 -> 12 sigma)

// ws layout (4B units):
//   counts int[N] | dinv f[N] | hs f[N*64] | part int[E] |
//   bsum int[392] | eoff int[392] | ecur int[391] | noff int[N]

// Per-block LDS bucket histogram -> few global atomics (391/block max).
__global__ __launch_bounds__(256) void k_bhist(const int* __restrict__ dst,
                                               int* __restrict__ bcnt) {
    __shared__ int lh[NB];
    const int t = threadIdx.x;
    const int e0 = blockIdx.x * EPB;
    for (int i = t; i < NB; i += 256) lh[i] = 0;
    __syncthreads();
#pragma unroll
    for (int i = 0; i < 16; i++) {
        int e = e0 + i * 256 + t;
        if (e < N_EDGES) atomicAdd(&lh[dst[e] >> 8], 1);
    }
    __syncthreads();
    for (int i = t; i < NB; i += 256) {
        int c = lh[i];
        if (c) atomicAdd(&bcnt[i], c);
    }
}

// Single block: exclusive scan of 391 bucket sums.
__global__ __launch_bounds__(512) void k_bscan(const int* __restrict__ bsum,
                                               int* __restrict__ eoff,
                                               int* __restrict__ ecur) {
    __shared__ int s[512];
    int t = threadIdx.x;
    int v = (t < NB) ? bsum[t] : 0;
    s[t] = v;
    __syncthreads();
    for (int d = 1; d < 512; d <<= 1) {
        int u = (t >= d) ? s[t - d] : 0;
        __syncthreads();
        s[t] += u;
        __syncthreads();
    }
    if (t < NB) {
        int excl = s[t] - v;
        eoff[t] = excl;
        ecur[t] = excl;
        if (t == NB - 1) eoff[NB] = s[t];
    }
}

// LDS-staged bucket partition: packed = (src<<8)|(dst&255), grouped by dst>>8.
__global__ __launch_bounds__(256) void k_part(const int* __restrict__ src,
                                              const int* __restrict__ dst,
                                              int* __restrict__ ecur,
                                              int* __restrict__ part) {
    __shared__ int lh[NB];
    __shared__ int lbase[NB + 1];
    __shared__ int ldelta[NB];
    __shared__ int lcur[NB];
    __shared__ int stage[EPB];
    __shared__ unsigned short sbk[EPB];
    const int t = threadIdx.x;
    const int e0 = blockIdx.x * EPB;
    for (int i = t; i < NB; i += 256) lh[i] = 0;
    __syncthreads();
    int p[16];
    short bk[16];
#pragma unroll
    for (int i = 0; i < 16; i++) {
        int e = e0 + i * 256 + t;
        bk[i] = -1;
        p[i] = 0;
        if (e < N_EDGES) {
            int s = src[e], d = dst[e];
            int b = d >> 8;
            bk[i] = (short)b;
            p[i] = (s << 8) | (d & 255);
            atomicAdd(&lh[b], 1);
        }
    }
    __syncthreads();
    // exclusive scan of lh[0..NB) by wave 0 (7 counters per lane)
    if (t < 64) {
        int c[7];
        int tot = 0;
#pragma unroll
        for (int j = 0; j < 7; j++) {
            int idx = t * 7 + j;
            c[j] = (idx < NB) ? lh[idx] : 0;
            tot += c[j];
        }
        int v = tot;
#pragma unroll
        for (int d = 1; d < 64; d <<= 1) {
            int u = __shfl_up(v, d);
            if (t >= d) v += u;
        }
        int run = v - tot;
#pragma unroll
        for (int j = 0; j < 7; j++) {
            int idx = t * 7 + j;
            if (idx < NB) lbase[idx] = run;
            run += c[j];
        }
        if (t == 63) lbase[NB] = run;  // total valid edges this block
    }
    __syncthreads();
    for (int i = t; i < NB; i += 256) {
        int cnt = lh[i];
        lcur[i] = lbase[i];
        if (cnt > 0) {
            int g = atomicAdd(&ecur[i], cnt);
            ldelta[i] = g - lbase[i];
        }
    }
    __syncthreads();
#pragma unroll
    for (int i = 0; i < 16; i++) {
        if (bk[i] >= 0) {
            int slot = atomicAdd(&lcur[bk[i]], 1);
            stage[slot] = p[i];
            sbk[slot] = (unsigned short)bk[i];
        }
    }
    __syncthreads();
    int nval = lbase[NB];
    for (int s = t; s < nval; s += 256) {
        part[ldelta[sbk[s]] + s] = stage[s];
    }
}

// One block per bucket: counting sort by dst low byte. Rewrites part[beg..end)
// in place as sorted src values; emits noff/counts/dinv per node (coalesced).
__global__ __launch_bounds__(256) void k_sort(const int* __restrict__ eoff,
                                              int* __restrict__ part,
                                              int* __restrict__ noff,
                                              int* __restrict__ counts,
                                              float* __restrict__ dinv) {
    __shared__ int lcnt[256], lcur[256];
    __shared__ int wsum[4];
    __shared__ int stage[BKT_CAP];
    const int t = threadIdx.x, b = blockIdx.x;
    const int beg = eoff[b], end = eoff[b + 1];
    const int m = end - beg;
    lcnt[t] = 0;
    __syncthreads();
    for (int i = t; i < m; i += 256) atomicAdd(&lcnt[part[beg + i] & 255], 1);
    __syncthreads();
    // exclusive scan of 256 counters
    int c = lcnt[t];
    int v = c;
    int lane = t & 63, w = t >> 6;
#pragma unroll
    for (int d = 1; d < 64; d <<= 1) {
        int u = __shfl_up(v, d);
        if (lane >= d) v += u;
    }
    if (lane == 63) wsum[w] = v;
    __syncthreads();
    int woff = 0;
#pragma unroll
    for (int k = 0; k < 4; k++) woff += (k < w) ? wsum[k] : 0;
    int excl = woff + v - c;
    lcur[t] = excl;
    int node = b * 256 + t;
    if (node < N_NODES) {
        noff[node] = beg + excl;
        counts[node] = c;
        dinv[node] = rsqrtf((float)c + 1.0f);
    }
    __syncthreads();
    for (int i = t; i < m; i += 256) {
        int pk = part[beg + i];
        int slot = atomicAdd(&lcur[pk & 255], 1);
        stage[slot] = pk >> 8;  // unpack src
    }
    __syncthreads();
    for (int i = t; i < m; i += 256) part[beg + i] = stage[i];
}

// GEMM: 16 rows/block (4 rows per wave), lane = output column.
// hs = (x@w) * dinv[row].
__global__ __launch_bounds__(256) void k_gemm(const float* __restrict__ x,
                                              const float* __restrict__ w,
                                              const float* __restrict__ dinv,
                                              float* __restrict__ hs) {
    __shared__ float wl[D_IN * D_OUT];  // 32 KB
    __shared__ float xl[16][D_IN];      // 8 KB
    const int t = threadIdx.x;
    for (int i = t; i < D_IN * D_OUT; i += 256) wl[i] = w[i];
    const int row0 = blockIdx.x * 16;
    const float4* xg = (const float4*)(x + (size_t)row0 * D_IN);
    float4* xs = (float4*)&xl[0][0];
    xs[t]       = xg[t];
    xs[t + 256] = xg[t + 256];
    __syncthreads();

    const int wave = t >> 6, lane = t & 63;
    const int r0 = wave * 4;
    float acc0 = 0.f, acc1 = 0.f, acc2 = 0.f, acc3 = 0.f;
#pragma unroll
    for (int k0 = 0; k0 < D_IN; k0 += 4) {
        float4 x0 = *(const float4*)&xl[r0 + 0][k0];
        float4 x1 = *(const float4*)&xl[r0 + 1][k0];
        float4 x2 = *(const float4*)&xl[r0 + 2][k0];
        float4 x3 = *(const float4*)&xl[r0 + 3][k0];
        float w0 = wl[(k0 + 0) * 64 + lane];
        float w1 = wl[(k0 + 1) * 64 + lane];
        float w2 = wl[(k0 + 2) * 64 + lane];
        float w3 = wl[(k0 + 3) * 64 + lane];
        acc0 = fmaf(x0.w, w3, fmaf(x0.z, w2, fmaf(x0.y, w1, fmaf(x0.x, w0, acc0))));
        acc1 = fmaf(x1.w, w3, fmaf(x1.z, w2, fmaf(x1.y, w1, fmaf(x1.x, w0, acc1))));
        acc2 = fmaf(x2.w, w3, fmaf(x2.z, w2, fmaf(x2.y, w1, fmaf(x2.x, w0, acc2))));
        acc3 = fmaf(x3.w, w3, fmaf(x3.z, w2, fmaf(x3.y, w1, fmaf(x3.x, w0, acc3))));
    }
    const int gr = row0 + r0;
    hs[(size_t)(gr + 0) * 64 + lane] = acc0 * dinv[gr + 0];
    hs[(size_t)(gr + 1) * 64 + lane] = acc1 * dinv[gr + 1];
    hs[(size_t)(gr + 2) * 64 + lane] = acc2 * dinv[gr + 2];
    hs[(size_t)(gr + 3) * 64 + lane] = acc3 * dinv[gr + 3];
}

// One wave per node, lane = output column. Register accumulation with 4
// independent accumulators; fused self-loop, dinv, bias, relu.
__global__ __launch_bounds__(256) void k_agg(const int* __restrict__ noff,
                                             const int* __restrict__ counts,
                                             const int* __restrict__ ssrc,
                                             const float* __restrict__ dinv,
                                             const float* __restrict__ hs,
                                             const float* __restrict__ bias,
                                             float* __restrict__ out) {
    int t = blockIdx.x * 256 + threadIdx.x;
    int node = t >> 6, lane = t & 63;
    if (node >= N_NODES) return;
    int beg = noff[node];
    int cnt = counts[node];
    float a0 = hs[(size_t)node * 64 + lane];  // self-loop term (carries dinv[node])
    float a1 = 0.f, a2 = 0.f, a3 = 0.f;
    for (int base = 0; base < cnt; base += 64) {
        int m = min(64, cnt - base);
        int sl = (base + lane < cnt) ? ssrc[beg + base + lane] : 0;
        int k = 0;
        for (; k + 4 <= m; k += 4) {
            int s0 = __shfl(sl, k), s1 = __shfl(sl, k + 1);
            int s2 = __shfl(sl, k + 2), s3 = __shfl(sl, k + 3);
            a0 += hs[(size_t)s0 * 64 + lane];
            a1 += hs[(size_t)s1 * 64 + lane];
            a2 += hs[(size_t)s2 * 64 + lane];
            a3 += hs[(size_t)s3 * 64 + lane];
        }
        for (; k < m; k++) {
            int s = __shfl(sl, k);
            a0 += hs[(size_t)s * 64 + lane];
        }
    }
    float dv = dinv[node];
    float vv = dv * (a0 + a1 + a2 + a3) + bias[lane];
    out[(size_t)node * 64 + lane] = vv > 0.f ? vv : 0.f;
}

extern "C" void kernel_launch(void* const* d_in, const int* in_sizes, int n_in,
                              void* d_out, int out_size, void* d_ws, size_t ws_size,
                              hipStream_t stream) {
    const float* x    = (const float*)d_in[0];
    const int*   ei   = (const int*)d_in[1];   // [2][E] row-major
    const float* w    = (const float*)d_in[2];
    const float* bias = (const float*)d_in[3];
    float* out = (float*)d_out;

    int*   counts = (int*)d_ws;                        // N
    float* dinv   = (float*)(counts + N_NODES);        // N
    float* hs     = dinv + N_NODES;                    // N*64
    int*   part   = (int*)(hs + (size_t)N_NODES * 64); // E
    int*   bsum   = part + N_EDGES;                    // 392
    int*   eoff   = bsum + 392;                        // NB+1
    int*   ecur   = eoff + 392;                        // NB
    int*   noff   = ecur + NB;                         // N

    const int* srcI = ei;
    const int* dstI = ei + N_EDGES;

    hipMemsetAsync(bsum, 0, NB * sizeof(int), stream);
    hipLaunchKernelGGL(k_bhist, dim3(NPART), dim3(256), 0, stream, dstI, bsum);
    hipLaunchKernelGGL(k_bscan, dim3(1), dim3(512), 0, stream, bsum, eoff, ecur);
    hipLaunchKernelGGL(k_part, dim3(NPART), dim3(256), 0, stream, srcI, dstI, ecur, part);
    hipLaunchKernelGGL(k_sort, dim3(NB), dim3(256), 0, stream, eoff, part, noff, counts, dinv);
    hipLaunchKernelGGL(k_gemm, dim3(N_NODES / 16), dim3(256), 0, stream, x, w, dinv, hs);
    hipLaunchKernelGGL(k_agg, dim3((N_NODES * 64) / 256), dim3(256), 0, stream,
                       noff, counts, part, dinv, hs, bias, out);
}

// Round 7
// 151.631 us; speedup vs baseline: 5.6466x; 1.0742x over previous
//
#include <hip/hip_runtime.h>
#include <hip/hip_fp16.h>

#define N_NODES 100000
#define N_EDGES 1600000
#define D_IN 128
#define D_OUT 64
#define NB 391          // ceil(100000/256) buckets of 256 dst nodes
#define EPB 4096        // edges per block in bhist/part
#define NPART 391       // ceil(1600000/4096)
#define BKT_CAP 4864    // max edges per bucket (mean 4096, sigma ~64 -> 12 sigma)

// ws layout (4B units):
//   counts int[N] | dinv f[N] | hs16 half[N*64] (=N*32 dwords) | part int[E] |
//   bsum int[392] | eoff int[392] | ecur int[391] | noff int[N]

// Per-block LDS bucket histogram -> few global atomics (391/block max).
__global__ __launch_bounds__(256) void k_bhist(const int* __restrict__ dst,
                                               int* __restrict__ bcnt) {
    __shared__ int lh[NB];
    const int t = threadIdx.x;
    const int e0 = blockIdx.x * EPB;
    for (int i = t; i < NB; i += 256) lh[i] = 0;
    __syncthreads();
#pragma unroll
    for (int i = 0; i < 16; i++) {
        int e = e0 + i * 256 + t;
        if (e < N_EDGES) atomicAdd(&lh[dst[e] >> 8], 1);
    }
    __syncthreads();
    for (int i = t; i < NB; i += 256) {
        int c = lh[i];
        if (c) atomicAdd(&bcnt[i], c);
    }
}

// Single block: exclusive scan of 391 bucket sums.
__global__ __launch_bounds__(512) void k_bscan(const int* __restrict__ bsum,
                                               int* __restrict__ eoff,
                                               int* __restrict__ ecur) {
    __shared__ int s[512];
    int t = threadIdx.x;
    int v = (t < NB) ? bsum[t] : 0;
    s[t] = v;
    __syncthreads();
    for (int d = 1; d < 512; d <<= 1) {
        int u = (t >= d) ? s[t - d] : 0;
        __syncthreads();
        s[t] += u;
        __syncthreads();
    }
    if (t < NB) {
        int excl = s[t] - v;
        eoff[t] = excl;
        ecur[t] = excl;
        if (t == NB - 1) eoff[NB] = s[t];
    }
}

// LDS-staged bucket partition: packed = (src<<8)|(dst&255), grouped by dst>>8.
__global__ __launch_bounds__(256) void k_part(const int* __restrict__ src,
                                              const int* __restrict__ dst,
                                              int* __restrict__ ecur,
                                              int* __restrict__ part) {
    __shared__ int lh[NB];
    __shared__ int lbase[NB + 1];
    __shared__ int ldelta[NB];
    __shared__ int lcur[NB];
    __shared__ int stage[EPB];
    __shared__ unsigned short sbk[EPB];
    const int t = threadIdx.x;
    const int e0 = blockIdx.x * EPB;
    for (int i = t; i < NB; i += 256) lh[i] = 0;
    __syncthreads();
    int p[16];
    short bk[16];
#pragma unroll
    for (int i = 0; i < 16; i++) {
        int e = e0 + i * 256 + t;
        bk[i] = -1;
        p[i] = 0;
        if (e < N_EDGES) {
            int s = src[e], d = dst[e];
            int b = d >> 8;
            bk[i] = (short)b;
            p[i] = (s << 8) | (d & 255);
            atomicAdd(&lh[b], 1);
        }
    }
    __syncthreads();
    // exclusive scan of lh[0..NB) by wave 0 (7 counters per lane)
    if (t < 64) {
        int c[7];
        int tot = 0;
#pragma unroll
        for (int j = 0; j < 7; j++) {
            int idx = t * 7 + j;
            c[j] = (idx < NB) ? lh[idx] : 0;
            tot += c[j];
        }
        int v = tot;
#pragma unroll
        for (int d = 1; d < 64; d <<= 1) {
            int u = __shfl_up(v, d);
            if (t >= d) v += u;
        }
        int run = v - tot;
#pragma unroll
        for (int j = 0; j < 7; j++) {
            int idx = t * 7 + j;
            if (idx < NB) lbase[idx] = run;
            run += c[j];
        }
        if (t == 63) lbase[NB] = run;  // total valid edges this block
    }
    __syncthreads();
    for (int i = t; i < NB; i += 256) {
        int cnt = lh[i];
        lcur[i] = lbase[i];
        if (cnt > 0) {
            int g = atomicAdd(&ecur[i], cnt);
            ldelta[i] = g - lbase[i];
        }
    }
    __syncthreads();
#pragma unroll
    for (int i = 0; i < 16; i++) {
        if (bk[i] >= 0) {
            int slot = atomicAdd(&lcur[bk[i]], 1);
            stage[slot] = p[i];
            sbk[slot] = (unsigned short)bk[i];
        }
    }
    __syncthreads();
    int nval = lbase[NB];
    for (int s = t; s < nval; s += 256) {
        part[ldelta[sbk[s]] + s] = stage[s];
    }
}

// One block per bucket: counting sort by dst low byte. Rewrites part[beg..end)
// in place as sorted src values; emits noff/counts/dinv per node (coalesced).
__global__ __launch_bounds__(256) void k_sort(const int* __restrict__ eoff,
                                              int* __restrict__ part,
                                              int* __restrict__ noff,
                                              int* __restrict__ counts,
                                              float* __restrict__ dinv) {
    __shared__ int lcnt[256], lcur[256];
    __shared__ int wsum[4];
    __shared__ int stage[BKT_CAP];
    const int t = threadIdx.x, b = blockIdx.x;
    const int beg = eoff[b], end = eoff[b + 1];
    const int m = end - beg;
    lcnt[t] = 0;
    __syncthreads();
    for (int i = t; i < m; i += 256) atomicAdd(&lcnt[part[beg + i] & 255], 1);
    __syncthreads();
    // exclusive scan of 256 counters
    int c = lcnt[t];
    int v = c;
    int lane = t & 63, w = t >> 6;
#pragma unroll
    for (int d = 1; d < 64; d <<= 1) {
        int u = __shfl_up(v, d);
        if (lane >= d) v += u;
    }
    if (lane == 63) wsum[w] = v;
    __syncthreads();
    int woff = 0;
#pragma unroll
    for (int k = 0; k < 4; k++) woff += (k < w) ? wsum[k] : 0;
    int excl = woff + v - c;
    lcur[t] = excl;
    int node = b * 256 + t;
    if (node < N_NODES) {
        noff[node] = beg + excl;
        counts[node] = c;
        dinv[node] = rsqrtf((float)c + 1.0f);
    }
    __syncthreads();
    for (int i = t; i < m; i += 256) {
        int pk = part[beg + i];
        int slot = atomicAdd(&lcur[pk & 255], 1);
        stage[slot] = pk >> 8;  // unpack src
    }
    __syncthreads();
    for (int i = t; i < m; i += 256) part[beg + i] = stage[i];
}

// GEMM: 16 rows/block (4 rows per wave), lane = output column.
// hs16 = fp16((x@w) * dinv[row]).
__global__ __launch_bounds__(256) void k_gemm(const float* __restrict__ x,
                                              const float* __restrict__ w,
                                              const float* __restrict__ dinv,
                                              __half* __restrict__ hs16) {
    __shared__ float wl[D_IN * D_OUT];  // 32 KB
    __shared__ float xl[16][D_IN];      // 8 KB
    const int t = threadIdx.x;
    for (int i = t; i < D_IN * D_OUT; i += 256) wl[i] = w[i];
    const int row0 = blockIdx.x * 16;
    const float4* xg = (const float4*)(x + (size_t)row0 * D_IN);
    float4* xs = (float4*)&xl[0][0];
    xs[t]       = xg[t];
    xs[t + 256] = xg[t + 256];
    __syncthreads();

    const int wave = t >> 6, lane = t & 63;
    const int r0 = wave * 4;
    float acc0 = 0.f, acc1 = 0.f, acc2 = 0.f, acc3 = 0.f;
#pragma unroll
    for (int k0 = 0; k0 < D_IN; k0 += 4) {
        float4 x0 = *(const float4*)&xl[r0 + 0][k0];
        float4 x1 = *(const float4*)&xl[r0 + 1][k0];
        float4 x2 = *(const float4*)&xl[r0 + 2][k0];
        float4 x3 = *(const float4*)&xl[r0 + 3][k0];
        float w0 = wl[(k0 + 0) * 64 + lane];
        float w1 = wl[(k0 + 1) * 64 + lane];
        float w2 = wl[(k0 + 2) * 64 + lane];
        float w3 = wl[(k0 + 3) * 64 + lane];
        acc0 = fmaf(x0.w, w3, fmaf(x0.z, w2, fmaf(x0.y, w1, fmaf(x0.x, w0, acc0))));
        acc1 = fmaf(x1.w, w3, fmaf(x1.z, w2, fmaf(x1.y, w1, fmaf(x1.x, w0, acc1))));
        acc2 = fmaf(x2.w, w3, fmaf(x2.z, w2, fmaf(x2.y, w1, fmaf(x2.x, w0, acc2))));
        acc3 = fmaf(x3.w, w3, fmaf(x3.z, w2, fmaf(x3.y, w1, fmaf(x3.x, w0, acc3))));
    }
    const int gr = row0 + r0;
    hs16[(size_t)(gr + 0) * 64 + lane] = __float2half(acc0 * dinv[gr + 0]);
    hs16[(size_t)(gr + 1) * 64 + lane] = __float2half(acc1 * dinv[gr + 1]);
    hs16[(size_t)(gr + 2) * 64 + lane] = __float2half(acc2 * dinv[gr + 2]);
    hs16[(size_t)(gr + 3) * 64 + lane] = __float2half(acc3 * dinv[gr + 3]);
}

// One wave per node, lane = output column. fp16 gather, fp32 accumulate,
// 4 independent accumulators; fused self-loop, dinv, bias, relu.
__global__ __launch_bounds__(256) void k_agg(const int* __restrict__ noff,
                                             const int* __restrict__ counts,
                                             const int* __restrict__ ssrc,
                                             const float* __restrict__ dinv,
                                             const __half* __restrict__ hs16,
                                             const float* __restrict__ bias,
                                             float* __restrict__ out) {
    int t = blockIdx.x * 256 + threadIdx.x;
    int node = t >> 6, lane = t & 63;
    if (node >= N_NODES) return;
    int beg = noff[node];
    int cnt = counts[node];
    float a0 = __half2float(hs16[(size_t)node * 64 + lane]);  // self-loop term
    float a1 = 0.f, a2 = 0.f, a3 = 0.f;
    for (int base = 0; base < cnt; base += 64) {
        int m = min(64, cnt - base);
        int sl = (base + lane < cnt) ? ssrc[beg + base + lane] : 0;
        int k = 0;
        for (; k + 4 <= m; k += 4) {
            int s0 = __shfl(sl, k), s1 = __shfl(sl, k + 1);
            int s2 = __shfl(sl, k + 2), s3 = __shfl(sl, k + 3);
            a0 += __half2float(hs16[(size_t)s0 * 64 + lane]);
            a1 += __half2float(hs16[(size_t)s1 * 64 + lane]);
            a2 += __half2float(hs16[(size_t)s2 * 64 + lane]);
            a3 += __half2float(hs16[(size_t)s3 * 64 + lane]);
        }
        for (; k < m; k++) {
            int s = __shfl(sl, k);
            a0 += __half2float(hs16[(size_t)s * 64 + lane]);
        }
    }
    float dv = dinv[node];
    float vv = dv * (a0 + a1 + a2 + a3) + bias[lane];
    out[(size_t)node * 64 + lane] = vv > 0.f ? vv : 0.f;
}

extern "C" void kernel_launch(void* const* d_in, const int* in_sizes, int n_in,
                              void* d_out, int out_size, void* d_ws, size_t ws_size,
                              hipStream_t stream) {
    const float* x    = (const float*)d_in[0];
    const int*   ei   = (const int*)d_in[1];   // [2][E] row-major
    const float* w    = (const float*)d_in[2];
    const float* bias = (const float*)d_in[3];
    float* out = (float*)d_out;

    int*    counts = (int*)d_ws;                         // N
    float*  dinv   = (float*)(counts + N_NODES);         // N
    __half* hs16   = (__half*)(dinv + N_NODES);          // N*64 halves = N*32 dwords
    int*    part   = (int*)((int*)(dinv + N_NODES) + N_NODES * 32);  // E
    int*    bsum   = part + N_EDGES;                     // 392
    int*    eoff   = bsum + 392;                         // NB+1
    int*    ecur   = eoff + 392;                         // NB
    int*    noff   = ecur + NB;                          // N

    const int* srcI = ei;
    const int* dstI = ei + N_EDGES;

    hipMemsetAsync(bsum, 0, NB * sizeof(int), stream);
    hipLaunchKernelGGL(k_bhist, dim3(NPART), dim3(256), 0, stream, dstI, bsum);
    hipLaunchKernelGGL(k_bscan, dim3(1), dim3(512), 0, stream, bsum, eoff, ecur);
    hipLaunchKernelGGL(k_part, dim3(NPART), dim3(256), 0, stream, srcI, dstI, ecur, part);
    hipLaunchKernelGGL(k_sort, dim3(NB), dim3(256), 0, stream, eoff, part, noff, counts, dinv);
    hipLaunchKernelGGL(k_gemm, dim3(N_NODES / 16), dim3(256), 0, stream, x, w, dinv, hs16);
    hipLaunchKernelGGL(k_agg, dim3((N_NODES * 64) / 256), dim3(256), 0, stream,
                       noff, counts, part, dinv, hs16, bias, out);
}